// Round 5
// baseline (263.618 us; speedup 1.0000x reference)
//
#include <hip/hip_runtime.h>

// InterestTransformerDecoder: B=512, L=L1=256, D=128. f32 I/O (R4 verified).
// R5: 3-kernel pipeline.
//  K1 <<<1024,256>>>: block=(batch, query-half of 128 rows). Streams 8 key-tiles
//     (bf16 K + transposed V in LDS, double-buffered), MFMA S and PV, fused
//     residual pooling from the f32 prefetch. Writes pooled partial to wsA.
//  K2 <<<1024,256>>>: block=(batch, key-half). Single pass over h2: w2=exp(cos2)*m1,
//     unnormalized num/den partials -> wsB.
//  K3 <<<512,128>>>: h=num/den, out=relu(h@W).
// ws usage: wsA f32[512][2][128] (512KB) + wsB f32[512][2][132] (528KB).

using u16 = unsigned short;
using u32 = unsigned int;
typedef __attribute__((ext_vector_type(8))) short bf16x8;
typedef __attribute__((ext_vector_type(4))) float f32x4;
typedef __attribute__((ext_vector_type(4))) u32 u32x4;
typedef __attribute__((ext_vector_type(2))) u32 u32x2;

#define KST 136   // Kbuf row stride (u16): 128 data + 8 pad
#define TST 40    // Tbuf row stride (u16): 32 data + 8 pad
#define WSTR 40   // WST row stride (u16)

__device__ __forceinline__ u16 f2bf(float f) {
  union { float f; u32 i; } v; v.f = f;
  u32 r = v.i + 0x7FFFu + ((v.i >> 16) & 1u);   // RNE
  return (u16)(r >> 16);
}
__device__ __forceinline__ bf16x8 as_bf(u32x4 x) {
  union { u32x4 u; bf16x8 b; } c; c.u = x; return c.b;
}
__device__ __forceinline__ u32x4 pack2(float4 a, float4 c) {
  u32x4 v;
  v.x = (u32)f2bf(a.x) | ((u32)f2bf(a.y) << 16);
  v.y = (u32)f2bf(a.z) | ((u32)f2bf(a.w) << 16);
  v.z = (u32)f2bf(c.x) | ((u32)f2bf(c.y) << 16);
  v.w = (u32)f2bf(c.z) | ((u32)f2bf(c.w) << 16);
  return v;
}
__device__ __forceinline__ float ssq2(float4 a, float4 c) {
  return a.x*a.x + a.y*a.y + a.z*a.z + a.w*a.w
       + c.x*c.x + c.y*c.y + c.z*c.z + c.w*c.w;
}
// pack 8 consecutive f32 -> 8 bf16, accumulate sum of squares
__device__ __forceinline__ u32x4 pack_bf8(const float* p, float& ss) {
  const float4 a = *(const float4*)p;
  const float4 c = *(const float4*)(p + 4);
  ss += ssq2(a, c);
  return pack2(a, c);
}

// Stage one 32-row j-tile row group: Kbuf row-major bf16, Tbuf transposed bf16,
// per-row inv-norm. rowb (wave-uniform) = tile-local base row of this 4-row group.
__device__ __forceinline__ void stage_tile(u32x4 v, float ss, u16* kb, u16* tb,
                                           float* invt, int rowb, int q, int m16) {
  const int row = rowb + q;
  *(u32x4*)&kb[row * KST + m16 * 8] = v;
  ss += __shfl_xor(ss, 1); ss += __shfl_xor(ss, 2);
  ss += __shfl_xor(ss, 4); ss += __shfl_xor(ss, 8);
  if (m16 == 0) invt[row] = rsqrtf(ss + 0.01f);
  u32 w0 = v.x, w1 = v.y, w2 = v.z, w3 = v.w;
  {  // 4x4 u32 transpose across the 4 q-lanes (xor 16, then xor 32)
    const int s1 = q & 1;
    u32 xa = s1 ? w0 : w1;
    u32 xb = s1 ? w2 : w3;
    xa = __shfl_xor(xa, 16);
    xb = __shfl_xor(xb, 16);
    if (s1) { w0 = xa; w2 = xb; } else { w1 = xa; w3 = xb; }
    const int s2 = q >> 1;
    u32 ya = s2 ? w0 : w2;
    u32 yb = s2 ? w1 : w3;
    ya = __shfl_xor(ya, 32);
    yb = __shfl_xor(yb, 32);
    if (s2) { w0 = ya; w1 = yb; } else { w2 = ya; w3 = yb; }
  }
  const int d0 = m16 * 8 + q * 2;      // d-row pair held by this lane
  u32x2 lo; lo.x = (w0 & 0xffffu) | (w1 << 16); lo.y = (w2 & 0xffffu) | (w3 << 16);
  u32x2 hi; hi.x = (w0 >> 16) | (w1 & 0xffff0000u); hi.y = (w2 >> 16) | (w3 & 0xffff0000u);
  *(u32x2*)&tb[d0 * TST + rowb]       = lo;
  *(u32x2*)&tb[(d0 + 1) * TST + rowb] = hi;
}

__global__ __launch_bounds__(256, 3)
void k1_self(const int* __restrict__ seq, const int* __restrict__ lastseq,
             const float* __restrict__ h1g, float* __restrict__ wsA) {
  __shared__ u16 Kbuf[2][32 * KST];     // 17408 B
  __shared__ u16 Tbuf[2][128 * TST];    // 20480 B
  __shared__ u16 WST[4][2 * 16 * WSTR]; // 10240 B; reused as RES f32[16][128]
  __shared__ float MK[256], LM[256], HLacc[128], INVt[2][32];

  const int blk  = blockIdx.x;
  const int b    = blk >> 1, half = blk & 1;
  const int t    = threadIdx.x;
  const int lane = t & 63, wv = t >> 6, q = lane >> 4, m16 = lane & 15;
  const float* h1b = h1g + (size_t)b * 32768;

  if (t < 128) HLacc[t] = 0.f;
  { float m = (seq[b * 256 + t] != 0) ? 1.f : 0.f;
    MK[t] = m; LM[t] = m * (float)lastseq[b * 256 + t]; }

  // Q fragments for this block's 128 query rows
  u32x4 av[2][4]; float invi[2][4];
  #pragma unroll
  for (int rt = 0; rt < 2; ++rt) {
    const int i0 = half * 128 + wv * 32 + rt * 16;
    float ss = 0.f;
    #pragma unroll
    for (int s = 0; s < 4; ++s)
      av[rt][s] = pack_bf8(&h1b[(i0 + m16) * 128 + s * 32 + q * 8], ss);
    ss += __shfl_xor(ss, 16);
    ss += __shfl_xor(ss, 32);
    const float invrow = rsqrtf(ss + 0.01f);
    #pragma unroll
    for (int r = 0; r < 4; ++r) invi[rt][r] = __shfl(invrow, q * 4 + r);
  }

  const int rl = t >> 4;        // 0..15 (staging row within 16-row step)
  const int sc = (t & 15) * 8;  // staging col base
  float racc[8] = {0.f,0.f,0.f,0.f,0.f,0.f,0.f,0.f};

  __syncthreads();   // LM/MK visible before racc/tile use

  // stage tile 0 (+ residual accumulation from f32)
  #pragma unroll
  for (int s = 0; s < 2; ++s) {
    const int rloc = s * 16 + rl;
    const float4 fa = *(const float4*)&h1b[rloc * 128 + sc];
    const float4 fb = *(const float4*)&h1b[rloc * 128 + sc + 4];
    if (half == 0) {
      const float l = LM[rloc];
      racc[0]+=l*fa.x; racc[1]+=l*fa.y; racc[2]+=l*fa.z; racc[3]+=l*fa.w;
      racc[4]+=l*fb.x; racc[5]+=l*fb.y; racc[6]+=l*fb.z; racc[7]+=l*fb.w;
    }
    stage_tile(pack2(fa, fb), ssq2(fa, fb), Kbuf[0], Tbuf[0], INVt[0],
               s * 16 + wv * 4, q, m16);
  }
  __syncthreads();

  const f32x4 fz = {0.f, 0.f, 0.f, 0.f};
  f32x4 acc[2][8];
  #pragma unroll
  for (int rt = 0; rt < 2; ++rt)
    #pragma unroll
    for (int dt = 0; dt < 8; ++dt) acc[rt][dt] = fz;
  float wpart[2][4] = {{0.f,0.f,0.f,0.f},{0.f,0.f,0.f,0.f}};
  u16* wst0 = &WST[wv][0];
  u16* wst1 = &WST[wv][16 * WSTR];

  for (int jt = 0; jt < 8; ++jt) {
    const int cur = jt & 1;
    float4 pa0, pb0, pa1, pb1;
    if (jt < 7) {   // prefetch next tile (16 f32/thread)
      const float* np = &h1b[(jt + 1) * 4096];
      pa0 = *(const float4*)&np[rl * 128 + sc];
      pb0 = *(const float4*)&np[rl * 128 + sc + 4];
      pa1 = *(const float4*)&np[(16 + rl) * 128 + sc];
      pb1 = *(const float4*)&np[(16 + rl) * 128 + sc + 4];
    }

    f32x4 Sa[2] = {fz, fz}, Sb[2] = {fz, fz};
    const u16* kb = Kbuf[cur];
    #pragma unroll
    for (int s = 0; s < 4; ++s) {
      bf16x8 ba = *(const bf16x8*)&kb[m16 * KST + s * 32 + q * 8];
      bf16x8 bb = *(const bf16x8*)&kb[(16 + m16) * KST + s * 32 + q * 8];
      bf16x8 a0 = as_bf(av[0][s]);
      bf16x8 a1 = as_bf(av[1][s]);
      Sa[0] = __builtin_amdgcn_mfma_f32_16x16x32_bf16(a0, ba, Sa[0], 0, 0, 0);
      Sb[0] = __builtin_amdgcn_mfma_f32_16x16x32_bf16(a0, bb, Sb[0], 0, 0, 0);
      Sa[1] = __builtin_amdgcn_mfma_f32_16x16x32_bf16(a1, ba, Sa[1], 0, 0, 0);
      Sb[1] = __builtin_amdgcn_mfma_f32_16x16x32_bf16(a1, bb, Sb[1], 0, 0, 0);
    }
    const float invja = INVt[cur][m16];
    const float invjb = INVt[cur][16 + m16];
    const float mja = MK[jt * 32 + m16];
    const float mjb = MK[jt * 32 + 16 + m16];
    #pragma unroll
    for (int rt = 0; rt < 2; ++rt) {
      u16* wr = rt ? wst1 : wst0;
      #pragma unroll
      for (int r = 0; r < 4; ++r) {
        const float wa = __expf(Sa[rt][r] * (invi[rt][r] * invja)) * mja;
        const float wb = __expf(Sb[rt][r] * (invi[rt][r] * invjb)) * mjb;
        wpart[rt][r] += wa + wb;
        wr[(q * 4 + r) * WSTR + m16]      = f2bf(wa);
        wr[(q * 4 + r) * WSTR + 16 + m16] = f2bf(wb);
      }
    }
    // LDS-only drain (NOT __threadfence_block: that waits vmcnt(0) and would
    // serialize the global prefetch into every iteration).
    asm volatile("s_waitcnt lgkmcnt(0)" ::: "memory");
    const bf16x8 aw0 = *(const bf16x8*)&wst0[m16 * WSTR + q * 8];
    const bf16x8 aw1 = *(const bf16x8*)&wst1[m16 * WSTR + q * 8];
    const u16* tb = Tbuf[cur];
    #pragma unroll
    for (int dt = 0; dt < 8; ++dt) {
      const bf16x8 bt = *(const bf16x8*)&tb[(dt * 16 + m16) * TST + q * 8];
      acc[0][dt] = __builtin_amdgcn_mfma_f32_16x16x32_bf16(aw0, bt, acc[0][dt], 0, 0, 0);
      acc[1][dt] = __builtin_amdgcn_mfma_f32_16x16x32_bf16(aw1, bt, acc[1][dt], 0, 0, 0);
    }
    if (jt < 7) {
      if (half == 0) {
        const float l0 = LM[(jt + 1) * 32 + rl];
        const float l1 = LM[(jt + 1) * 32 + 16 + rl];
        racc[0]+=l0*pa0.x+l1*pa1.x; racc[1]+=l0*pa0.y+l1*pa1.y;
        racc[2]+=l0*pa0.z+l1*pa1.z; racc[3]+=l0*pa0.w+l1*pa1.w;
        racc[4]+=l0*pb0.x+l1*pb1.x; racc[5]+=l0*pb0.y+l1*pb1.y;
        racc[6]+=l0*pb0.z+l1*pb1.z; racc[7]+=l0*pb0.w+l1*pb1.w;
      }
      stage_tile(pack2(pa0, pb0), ssq2(pa0, pb0), Kbuf[cur ^ 1], Tbuf[cur ^ 1],
                 INVt[cur ^ 1], wv * 4, q, m16);
      stage_tile(pack2(pa1, pb1), ssq2(pa1, pb1), Kbuf[cur ^ 1], Tbuf[cur ^ 1],
                 INVt[cur ^ 1], 16 + wv * 4, q, m16);
    }
    __syncthreads();
  }

  // pooled self-attn epilogue
  #pragma unroll
  for (int rt = 0; rt < 2; ++rt) {
    const int i0 = half * 128 + wv * 32 + rt * 16;
    float rws[4];
    #pragma unroll
    for (int r = 0; r < 4; ++r) {
      float s = wpart[rt][r];
      s += __shfl_xor(s, 1); s += __shfl_xor(s, 2);
      s += __shfl_xor(s, 4); s += __shfl_xor(s, 8);
      rws[r] = 1.f / s;
    }
    #pragma unroll
    for (int dt = 0; dt < 8; ++dt) {
      float v = 0.f;
      #pragma unroll
      for (int r = 0; r < 4; ++r)
        v += acc[rt][dt][r] * rws[r] * LM[i0 + q * 4 + r];
      v += __shfl_xor(v, 16);
      v += __shfl_xor(v, 32);
      if (q == 0) atomicAdd(&HLacc[dt * 16 + m16], v);
    }
  }
  __syncthreads();           // HLacc complete; WST now free
  if (half == 0) {           // residual partial -> LDS for cross-thread reduce
    float* RES = (float*)WST;   // f32[16][128]
    float4 r0 = {racc[0], racc[1], racc[2], racc[3]};
    float4 r1 = {racc[4], racc[5], racc[6], racc[7]};
    *(float4*)&RES[rl * 128 + sc]     = r0;
    *(float4*)&RES[rl * 128 + sc + 4] = r1;
  }
  __syncthreads();
  if (t < 128) {
    float vv = HLacc[t];
    if (half == 0) {
      const float* RES = (const float*)WST;
      #pragma unroll
      for (int r = 0; r < 16; ++r) vv += RES[r * 128 + t];
    }
    wsA[b * 256 + half * 128 + t] = vv;
  }
}

__global__ __launch_bounds__(256)
void k2_cross(const int* __restrict__ seq1, const float* __restrict__ h2g,
              const float* __restrict__ wsA, float* __restrict__ wsB) {
  __shared__ float HL[128], W2[128], PS[2][128], SCs[2];
  const int blk = blockIdx.x, b = blk >> 1, kh = blk & 1;
  const int t = threadIdx.x;
  if (t < 128) HL[t] = wsA[b * 256 + t] + wsA[b * 256 + 128 + t];
  __syncthreads();
  if (t < 64) {
    float s = HL[t] * HL[t] + HL[t + 64] * HL[t + 64];
    s += __shfl_xor(s, 1); s += __shfl_xor(s, 2); s += __shfl_xor(s, 4);
    s += __shfl_xor(s, 8); s += __shfl_xor(s, 16); s += __shfl_xor(s, 32);
    if (t == 0) SCs[0] = rsqrtf(s + 0.01f);
  }
  __syncthreads();
  const float* h2b = h2g + (size_t)b * 32768;
  {
    const int kl = t >> 1, h64 = t & 1;    // 128 keys, 2 threads each
    const float4* r = (const float4*)(h2b + (size_t)(kh * 128 + kl) * 128 + h64 * 64);
    const float* hl = &HL[h64 * 64];
    float dot = 0.f, ss = 0.f;
    #pragma unroll
    for (int ii = 0; ii < 16; ++ii) {
      const float4 vv = r[ii];
      dot += vv.x * hl[ii*4] + vv.y * hl[ii*4+1] + vv.z * hl[ii*4+2] + vv.w * hl[ii*4+3];
      ss  += vv.x*vv.x + vv.y*vv.y + vv.z*vv.z + vv.w*vv.w;
    }
    dot += __shfl_xor(dot, 1);
    ss  += __shfl_xor(ss, 1);
    if (h64 == 0) {
      const float mk = (seq1[b * 256 + kh * 128 + kl] != 0) ? 1.f : 0.f;
      W2[kl] = __expf(dot * rsqrtf(ss + 0.01f) * SCs[0]) * mk;
    }
  }
  __syncthreads();
  if (t < 64) {
    float s = W2[t] + W2[t + 64];
    s += __shfl_xor(s, 1); s += __shfl_xor(s, 2); s += __shfl_xor(s, 4);
    s += __shfl_xor(s, 8); s += __shfl_xor(s, 16); s += __shfl_xor(s, 32);
    if (t == 0) SCs[1] = s;
  }
  {
    const int d = t & 127, kg = t >> 7;    // 2 groups x 64 keys
    float p = 0.f;
    #pragma unroll 8
    for (int n = 0; n < 64; ++n)
      p += W2[kg * 64 + n] * h2b[(size_t)(kh * 128 + kg * 64 + n) * 128 + d];
    PS[kg][d] = p;
  }
  __syncthreads();
  if (t < 128) wsB[(b * 2 + kh) * 132 + t] = PS[0][t] + PS[1][t];
  if (t == 128) wsB[(b * 2 + kh) * 132 + 128] = SCs[1];
}

__global__ __launch_bounds__(128)
void k3_out(const float* __restrict__ wsB, const float* __restrict__ wg,
            float* __restrict__ outg) {
  __shared__ float HH[128];
  const int b = blockIdx.x, t = threadIdx.x;
  const float den = wsB[(b * 2) * 132 + 128] + wsB[(b * 2 + 1) * 132 + 128];
  HH[t] = (wsB[(b * 2) * 132 + t] + wsB[(b * 2 + 1) * 132 + t]) / den;
  __syncthreads();
  float o = 0.f;
  #pragma unroll 8
  for (int d = 0; d < 128; ++d)
    o += HH[d] * wg[d * 128 + t];
  outg[(size_t)b * 128 + t] = fmaxf(o, 0.f);
}

extern "C" void kernel_launch(void* const* d_in, const int* in_sizes, int n_in,
                              void* d_out, int out_size, void* d_ws, size_t ws_size,
                              hipStream_t stream) {
  (void)in_sizes; (void)n_in; (void)ws_size; (void)out_size;
  const int*   seq     = (const int*)d_in[0];
  const int*   lastseq = (const int*)d_in[1];
  const int*   seq1    = (const int*)d_in[2];
  const float* h1      = (const float*)d_in[3];
  const float* h2      = (const float*)d_in[4];
  const float* w       = (const float*)d_in[5];
  float* out = (float*)d_out;
  float* wsA = (float*)d_ws;            // 512*2*128 = 131072 f32
  float* wsB = wsA + 131072;            // 512*2*132 = 135168 f32
  k1_self<<<dim3(1024), dim3(256), 0, stream>>>(seq, lastseq, h1, wsA);
  k2_cross<<<dim3(1024), dim3(256), 0, stream>>>(seq1, h2, wsA, wsB);
  k3_out<<<dim3(512), dim3(128), 0, stream>>>(wsB, w, out);
}